// Round 5
// baseline (288.427 us; speedup 1.0000x reference)
//
#include <hip/hip_runtime.h>
#include <cmath>

#define NPTS 262144
#define NLVL 16
#define TBL  524288u
#define TMASK 524287u
#define TPB  128   // points per block (k2)

typedef __attribute__((ext_vector_type(8))) short short8;
typedef __attribute__((ext_vector_type(4))) float f32x4;

struct ResArr { float r[NLVL]; };

__device__ __forceinline__ unsigned short f2bf(float f) {
    union { float f; unsigned u; } v; v.f = f;
    unsigned r = v.u + 0x7FFFu + ((v.u >> 16) & 1u);   // RNE
    return (unsigned short)(r >> 16);
}

#define MFMA(a,b,c) __builtin_amdgcn_mfma_f32_16x16x32_bf16((a),(b),(c),0,0,0)

// ---------------------------------------------------------------------------
// Kernel 1: hash-grid encode, XCD-pinned by level, 2 points/thread.
// block b -> XCD (b&7); level = (b&7) [+8 for 2nd half of steps].
// 16 independent gathers in flight per thread; same level -> same L2 slab.
// ---------------------------------------------------------------------------
__global__ __launch_bounds__(256) void hash_encode_k(
    const float* __restrict__ coords,
    const float* __restrict__ emb,
    unsigned* __restrict__ featws,
    ResArr res)
{
    const int b    = blockIdx.x;
    const int xcd  = b & 7;
    const int step = b >> 3;                    // 0..1023
    const int l    = (step < 512) ? xcd : (xcd + 8);
    const int p0   = (step & 511) * 512 + threadIdx.x;   // pts p0, p0+256

    const float r = res.r[l];
    const unsigned base = (unsigned)l * TBL;
    const float2* __restrict__ emb2 = (const float2*)emb;

    unsigned idxs[16];
    float    wgt[16];
    #pragma unroll
    for (int t = 0; t < 2; ++t) {
        const int p = p0 + t*256;
        const float cx = coords[3*p], cy = coords[3*p+1], cz = coords[3*p+2];
        const float px = cx*r, py = cy*r, pz = cz*r;
        const float fpx = floorf(px), fpy = floorf(py), fpz = floorf(pz);
        const float fx = px-fpx, fy = py-fpy, fz = pz-fpz;
        const unsigned ix=(unsigned)fpx, iy=(unsigned)fpy, iz=(unsigned)fpz;
        const unsigned hx0=ix,             hx1=ix+1u;
        const unsigned hy0=iy*2654435761u, hy1=(iy+1u)*2654435761u;
        const unsigned hz0=iz*805459861u,  hz1=(iz+1u)*805459861u;
        idxs[t*8+0] = base + ((hx0^hy0^hz0)&TMASK);
        idxs[t*8+1] = base + ((hx0^hy0^hz1)&TMASK);
        idxs[t*8+2] = base + ((hx0^hy1^hz0)&TMASK);
        idxs[t*8+3] = base + ((hx0^hy1^hz1)&TMASK);
        idxs[t*8+4] = base + ((hx1^hy0^hz0)&TMASK);
        idxs[t*8+5] = base + ((hx1^hy0^hz1)&TMASK);
        idxs[t*8+6] = base + ((hx1^hy1^hz0)&TMASK);
        idxs[t*8+7] = base + ((hx1^hy1^hz1)&TMASK);
        const float wx0=1.f-fx, wy0=1.f-fy, wz0=1.f-fz;
        wgt[t*8+0]=wx0*wy0*wz0; wgt[t*8+1]=wx0*wy0*fz;
        wgt[t*8+2]=wx0*fy*wz0;  wgt[t*8+3]=wx0*fy*fz;
        wgt[t*8+4]=fx*wy0*wz0;  wgt[t*8+5]=fx*wy0*fz;
        wgt[t*8+6]=fx*fy*wz0;   wgt[t*8+7]=fx*fy*fz;
    }

    float2 f[16];
    #pragma unroll
    for (int j = 0; j < 16; ++j) f[j] = emb2[idxs[j]];

    #pragma unroll
    for (int t = 0; t < 2; ++t) {
        float o0 = 0.f, o1 = 0.f;
        #pragma unroll
        for (int c = 0; c < 8; ++c) {
            o0 = fmaf(wgt[t*8+c], f[t*8+c].x, o0);
            o1 = fmaf(wgt[t*8+c], f[t*8+c].y, o1);
        }
        featws[(size_t)l * NPTS + p0 + t*256] =
            (unsigned)f2bf(o0) | ((unsigned)f2bf(o1) << 16);
    }
}

// ---------------------------------------------------------------------------
// Kernel 2: MFMA MLP chain (density + SH + color). 128 points/block. (~33us)
// ---------------------------------------------------------------------------
__global__ __launch_bounds__(256, 3) void mlp_mfma_k(
    const unsigned* __restrict__ featws,
    const float* __restrict__ dirs,
    const float* __restrict__ dw1, const float* __restrict__ db1,
    const float* __restrict__ dw2, const float* __restrict__ db2,
    const float* __restrict__ cw1, const float* __restrict__ cb1,
    const float* __restrict__ cw2, const float* __restrict__ cb2,
    const float* __restrict__ cw3, const float* __restrict__ cb3,
    const float* __restrict__ cw4, const float* __restrict__ cb4,
    float* __restrict__ out)
{
    const int tid  = threadIdx.x;
    const int wid  = tid >> 6;
    const int lane = tid & 63;
    const int m16  = lane & 15;
    const int q    = lane >> 4;

    __shared__ __align__(16) unsigned short wlds[28 * 512];
    __shared__ float blds[288];
    __shared__ __align__(16) unsigned short featL[TPB * 40];   // [pt][32+8 pad] bf16
    __shared__ __align__(16) unsigned short actL[4 * 16 * 72]; // per-wave [16][64+8] bf16

    const unsigned char MAT[28] = {0,0,0,0, 1,1, 2,2,2,2, 3,3,3,3,3,3,3,3, 4,4,4,4,4,4,4,4, 5,5};
    const unsigned char K0 [28] = {0,0,0,0, 0,32, 0,0,0,0, 0,0,0,0,32,32,32,32, 0,0,0,0,32,32,32,32, 0,32};
    const unsigned char N0 [28] = {0,16,32,48, 0,0, 0,16,32,48, 0,16,32,48,0,16,32,48, 0,16,32,48,0,16,32,48, 0,0};

    #pragma unroll
    for (int s = 0; s < 28; ++s) {
        if ((s & 3) == wid) {
            const int mat = MAT[s];
            const float* src = mat==0?dw1 : mat==1?dw2 : mat==2?cw1 : mat==3?cw2 : mat==4?cw3 : cw4;
            const int fan = (mat==1) ? 16 : (mat==5) ? 3 : 64;
            const int k = (int)K0[s] + q*8;
            const int n = (int)N0[s] + m16;
            unsigned short u[8];
            #pragma unroll
            for (int j = 0; j < 8; ++j) {
                float v = 0.f;
                if (mat != 5 || n < 3) v = src[(k+j)*fan + n];
                u[j] = f2bf(v);
            }
            unsigned* w32 = (unsigned*)(wlds + s*512 + lane*8);
            w32[0] = (unsigned)u[0] | ((unsigned)u[1] << 16);
            w32[1] = (unsigned)u[2] | ((unsigned)u[3] << 16);
            w32[2] = (unsigned)u[4] | ((unsigned)u[5] << 16);
            w32[3] = (unsigned)u[6] | ((unsigned)u[7] << 16);
        }
    }
    {
        int t = tid;
        if      (t <  64) blds[t] = db1[t];
        else if (t <  80) blds[t] = db2[t-64];
        else if (t < 144) blds[t] = cb1[t-80];
        else if (t < 208) blds[t] = cb2[t-144];
    }
    if (tid < 80) {
        int t = tid + 208;
        if (t < 272) blds[t] = cb3[t-208];
        else         blds[t] = (t-272 < 3) ? cb4[t-272] : 0.f;
    }

    const int pbase = blockIdx.x * TPB;
    unsigned* fL32 = (unsigned*)featL;        // row stride 20 uints
    #pragma unroll
    for (int j = 0; j < 8; ++j) {
        const int idx  = j*256 + tid;
        const int l    = idx >> 7;
        const int ploc = idx & 127;
        fL32[ploc*20 + l] = featws[(size_t)l * NPTS + pbase + ploc];
    }
    __syncthreads();

    unsigned short* aw = actL + wid*1152;     // 16 x 72
    const short8* wfr = (const short8*)wlds;  // B(s) = wfr[s*64 + lane]

    #pragma unroll
    for (int iter = 0; iter < 2; ++iter) {
        const int tile = wid + 4*iter;
        const int loc0 = tile*16;
        const int p0g  = pbase + loc0;

        // ---- density L1: feat(32) -> 64, relu ----
        short8 a0 = *(const short8*)(featL + (loc0+m16)*40 + q*8);
        f32x4 acc[4];
        #pragma unroll
        for (int nc = 0; nc < 4; ++nc) {
            const float b = blds[nc*16 + m16];
            acc[nc] = (f32x4){b,b,b,b};
            acc[nc] = MFMA(a0, wfr[nc*64 + lane], acc[nc]);
        }
        #pragma unroll
        for (int nc = 0; nc < 4; ++nc)
            #pragma unroll
            for (int r = 0; r < 4; ++r)
                aw[(q*4+r)*72 + nc*16 + m16] = f2bf(fmaxf(acc[nc][r], 0.f));

        // ---- density L2: 64 -> 16 (no act) ----
        short8 ad0 = *(const short8*)(aw + m16*72 + q*8);
        short8 ad1 = *(const short8*)(aw + m16*72 + 32 + q*8);
        f32x4 dob;
        { const float b = blds[64 + m16]; dob = (f32x4){b,b,b,b}; }
        dob = MFMA(ad0, wfr[4*64 + lane], dob);
        dob = MFMA(ad1, wfr[5*64 + lane], dob);

        if (m16 == 0) {
            #pragma unroll
            for (int r = 0; r < 4; ++r) out[p0g + q*4 + r] = expf(dob[r]);
        }

        // ---- build inp = [SH(16) | dob(16)] ----
        #pragma unroll
        for (int r = 0; r < 4; ++r)
            aw[(q*4+r)*72 + 16 + m16] = f2bf(dob[r]);
        {
            const int pg = p0g + m16;
            const float dx0 = dirs[3*pg], dy0 = dirs[3*pg+1], dz0 = dirs[3*pg+2];
            const float inv = 1.f / sqrtf(dx0*dx0 + dy0*dy0 + dz0*dz0);
            float x = dx0*inv, y = dy0*inv, z = dz0*inv;
            x = ((x+1.f)*0.5f)*2.f - 1.f;
            y = ((y+1.f)*0.5f)*2.f - 1.f;
            z = ((z+1.f)*0.5f)*2.f - 1.f;
            float s0, s1, s2, s3;
            switch (q) {
            case 0: s0 = 0.28209479177387814f;
                    s1 = -0.48860251190291987f*y;
                    s2 =  0.48860251190291987f*z;
                    s3 = -0.48860251190291987f*x; break;
            case 1: s0 =  1.0925484305920792f*x*y;
                    s1 = -1.0925484305920792f*y*z;
                    s2 =  0.94617469575756f*z*z - 0.31539156525252f;
                    s3 = -1.0925484305920792f*x*z; break;
            case 2: s0 =  0.5462742152960396f*(x*x - y*y);
                    s1 =  0.5900435899266435f*y*(-3.f*x*x + y*y);
                    s2 =  2.890611442640554f*x*y*z;
                    s3 =  0.4570457994644657f*y*(1.f - 5.f*z*z); break;
            default:s0 =  0.3731763325901154f*z*(5.f*z*z - 3.f);
                    s1 =  0.4570457994644657f*x*(1.f - 5.f*z*z);
                    s2 =  1.445305721320277f*z*(x*x - y*y);
                    s3 =  0.5900435899266435f*x*(x*x - 3.f*y*y); break;
            }
            unsigned* ip = (unsigned*)(aw + m16*72 + q*4);
            ip[0] = (unsigned)f2bf(s0) | ((unsigned)f2bf(s1) << 16);
            ip[1] = (unsigned)f2bf(s2) | ((unsigned)f2bf(s3) << 16);
        }

        // ---- color L1: inp(32) -> 64, relu ----
        short8 ac0 = *(const short8*)(aw + m16*72 + q*8);
        #pragma unroll
        for (int nc = 0; nc < 4; ++nc) {
            const float b = blds[80 + nc*16 + m16];
            acc[nc] = (f32x4){b,b,b,b};
            acc[nc] = MFMA(ac0, wfr[(6+nc)*64 + lane], acc[nc]);
        }
        #pragma unroll
        for (int nc = 0; nc < 4; ++nc)
            #pragma unroll
            for (int r = 0; r < 4; ++r)
                aw[(q*4+r)*72 + nc*16 + m16] = f2bf(fmaxf(acc[nc][r], 0.f));

        // ---- color L2: 64 -> 64, relu ----
        short8 a20 = *(const short8*)(aw + m16*72 + q*8);
        short8 a21 = *(const short8*)(aw + m16*72 + 32 + q*8);
        #pragma unroll
        for (int nc = 0; nc < 4; ++nc) {
            const float b = blds[144 + nc*16 + m16];
            acc[nc] = (f32x4){b,b,b,b};
            acc[nc] = MFMA(a20, wfr[(10+nc)*64 + lane], acc[nc]);
            acc[nc] = MFMA(a21, wfr[(14+nc)*64 + lane], acc[nc]);
        }
        #pragma unroll
        for (int nc = 0; nc < 4; ++nc)
            #pragma unroll
            for (int r = 0; r < 4; ++r)
                aw[(q*4+r)*72 + nc*16 + m16] = f2bf(fmaxf(acc[nc][r], 0.f));

        // ---- color L3: 64 -> 64, relu ----
        short8 a30 = *(const short8*)(aw + m16*72 + q*8);
        short8 a31 = *(const short8*)(aw + m16*72 + 32 + q*8);
        #pragma unroll
        for (int nc = 0; nc < 4; ++nc) {
            const float b = blds[208 + nc*16 + m16];
            acc[nc] = (f32x4){b,b,b,b};
            acc[nc] = MFMA(a30, wfr[(18+nc)*64 + lane], acc[nc]);
            acc[nc] = MFMA(a31, wfr[(22+nc)*64 + lane], acc[nc]);
        }
        #pragma unroll
        for (int nc = 0; nc < 4; ++nc)
            #pragma unroll
            for (int r = 0; r < 4; ++r)
                aw[(q*4+r)*72 + nc*16 + m16] = f2bf(fmaxf(acc[nc][r], 0.f));

        // ---- color L4: 64 -> 3 (padded to 16), sigmoid ----
        short8 a40 = *(const short8*)(aw + m16*72 + q*8);
        short8 a41 = *(const short8*)(aw + m16*72 + 32 + q*8);
        f32x4 c4;
        { const float b = blds[272 + m16]; c4 = (f32x4){b,b,b,b}; }
        c4 = MFMA(a40, wfr[26*64 + lane], c4);
        c4 = MFMA(a41, wfr[27*64 + lane], c4);
        if (m16 < 3) {
            #pragma unroll
            for (int r = 0; r < 4; ++r)
                out[NPTS + 3*(p0g + q*4 + r) + m16] = 1.f / (1.f + expf(-c4[r]));
        }
    }
}

extern "C" void kernel_launch(void* const* d_in, const int* in_sizes, int n_in,
                              void* d_out, int out_size, void* d_ws, size_t ws_size,
                              hipStream_t stream)
{
    // RES must bit-match numpy: floor(16 * b**l) in f64, b = exp((ln512-ln16)/15).
    ResArr res;
    const double b = exp((log(512.0) - log(16.0)) / 15.0);
    for (int l = 0; l < NLVL; ++l)
        res.r[l] = (float)floor(16.0 * pow(b, (double)l));

    unsigned* featws = (unsigned*)d_ws;   // 16 * 262144 * 4 B = 16.8 MB

    hash_encode_k<<<8192, 256, 0, stream>>>(
        (const float*)d_in[0],   // coords
        (const float*)d_in[2],   // embeddings
        featws, res);

    mlp_mfma_k<<<NPTS/TPB, 256, 0, stream>>>(
        featws,
        (const float*)d_in[1],   // directions
        (const float*)d_in[3],  (const float*)d_in[4],   // dw1, db1
        (const float*)d_in[5],  (const float*)d_in[6],   // dw2, db2
        (const float*)d_in[7],  (const float*)d_in[8],   // cw1, cb1
        (const float*)d_in[9],  (const float*)d_in[10],  // cw2, cb2
        (const float*)d_in[11], (const float*)d_in[12],  // cw3, cb3
        (const float*)d_in[13], (const float*)d_in[14],  // cw4, cb4
        (float*)d_out);
}